// Round 6
// baseline (906.532 us; speedup 1.0000x reference)
//
#include <hip/hip_runtime.h>
#include <math.h>

// LIF_13984413516471 — exact serial chain, 1 batch per wave, window-level
// certified quiet fast path, 8-window-deep register rotation (load prefetch
// + store-register rotation). B=128, S=128, H=128, K=8.
// Reference: one scalar accumulator per batch, sequential over (i,j,k);
// per substep: s += x; if (s > th[k]) s = 0.
// Outputs (B,S,K,H) fp32: outs | spikes. Bitwise-exact fp32 replay.

#define NB 128
#define NS 128
#define NH 128
#define NK 8
#define NT (NS * NH)            // 16384 t-positions per batch
#define WL 8                    // window = 8 t-steps (64 substeps)
#define NW2 (NT / WL)           // 2048 windows per batch
#define GD 8                    // group depth (windows per rotation group)
#define NG (NW2 / GD)           // 256 groups
#define OUTN ((size_t)NB * NS * NK * NH)

// ---- ws layout (floats) ----
#define WS_M     0                      // M    [NB][NW2]
#define WS_SREC  (NB * NW2)             // s_rec[NB][NT]
#define WS_TOTAL (NB * NW2 + NB * NT)

// Per-(b,window) quiet bound, f64: M = minth - maxPrefix - margin where
// maxPrefix >= max prefix sum of the 64 substep adds from window entry.
// If entering s <= M, the real-arith chain stays >= margin below minth all
// window; fp32 drift over 64 adds at |s|<=26000 is < 0.1 = margin, so the
// fp32 chain provably never spikes -> pure adds are bitwise-exact.
__global__ void lif_bounds8(const float* __restrict__ x,
                            const float* __restrict__ th,
                            float* __restrict__ M)
{
    int idx = blockIdx.x * 256 + threadIdx.x;   // flat over NB*NW2
    if (idx >= NB * NW2) return;
    float minth = th[0];
#pragma unroll
    for (int k = 1; k < NK; ++k) minth = fminf(minth, th[k]);
    const float* xp = x + (size_t)idx * WL;     // idx = b*NW2 + w -> x[b][w*8]
    double p = 0.0, maxp = -1e300;
#pragma unroll
    for (int l = 0; l < WL; ++l) {
        double xv = (double)xp[l];
#pragma unroll
        for (int k = 0; k < NK; ++k) { p += xv; maxp = fmax(maxp, p); }
    }
    M[idx] = (float)((double)minth - maxp - 0.1 - 1e-6 * fabs(maxp));
}

#define ADD8(xv) do { s += xv; s += xv; s += xv; s += xv; \
                      s += xv; s += xv; s += xv; s += xv; } while (0)
#define STEP8(xv) do { \
    s += xv; s = (s > th0) ? 0.0f : s; \
    s += xv; s = (s > th1) ? 0.0f : s; \
    s += xv; s = (s > th2) ? 0.0f : s; \
    s += xv; s = (s > th3) ? 0.0f : s; \
    s += xv; s = (s > th4) ? 0.0f : s; \
    s += xv; s = (s > th5) ? 0.0f : s; \
    s += xv; s = (s > th6) ? 0.0f : s; \
    s += xv; s = (s > th7) ? 0.0f : s; } while (0)

// Serial chain: one batch per wave, lane 0 carries the state. Groups of 8
// windows: all of next group's loads issue at group top (~2300 cyc slack
// covers HBM miss); each window slot has its own store registers (vmcnt
// waits amortize over 8 windows). Window-level vote via readfirstlane ->
// s_cbranch (not if-convertible). Fast: 64 pure dependent adds (bitwise
// identical when certified spike-free). Slow: 64 exact substeps.
__global__ void __launch_bounds__(64, 1)
lif_chain(const float* __restrict__ x, const float* __restrict__ th,
          const float* __restrict__ M, float* __restrict__ s_rec)
{
    if (threadIdx.x != 0) return;
    int b = blockIdx.x;
    const float4* xb = (const float4*)(x + (size_t)b * NT);
    const float*  Mb = M + (size_t)b * NW2;
    float*        sb = s_rec + (size_t)b * NT;

    const float th0 = th[0], th1 = th[1], th2 = th[2], th3 = th[3];
    const float th4 = th[4], th5 = th[5], th6 = th[6], th7 = th[7];

    float s = 0.0f;
    float4 cx0[GD], cx1[GD], nx0[GD], nx1[GD];
    float  cM[GD], nM[GD];

#pragma unroll
    for (int l = 0; l < GD; ++l) {
        cx0[l] = xb[2 * l];
        cx1[l] = xb[2 * l + 1];
        cM[l]  = Mb[l];
    }

    for (int g = 0; g < NG; ++g) {
        // issue ALL of next group's loads now (clamped refetch on last group)
        const int gn = (g + 1 < NG) ? (g + 1) : g;
#pragma unroll
        for (int l = 0; l < GD; ++l) {
            int w = gn * GD + l;
            nx0[l] = xb[2 * w];
            nx1[l] = xb[2 * w + 1];
            nM[l]  = Mb[w];
        }
#pragma unroll
        for (int l = 0; l < GD; ++l) {
            const int w = g * GD + l;
            float4 r0, r1;     // per-slot store regs (reused 8 windows later)
            int q = __builtin_amdgcn_readfirstlane((int)(s <= cM[l]));
            if (q) {
                // certified spike-free window: pure adds (bitwise identical)
                r0.x = s; ADD8(cx0[l].x);
                r0.y = s; ADD8(cx0[l].y);
                r0.z = s; ADD8(cx0[l].z);
                r0.w = s; ADD8(cx0[l].w);
                r1.x = s; ADD8(cx1[l].x);
                r1.y = s; ADD8(cx1[l].y);
                r1.z = s; ADD8(cx1[l].z);
                r1.w = s; ADD8(cx1[l].w);
            } else {
                r0.x = s; STEP8(cx0[l].x);
                r0.y = s; STEP8(cx0[l].y);
                r0.z = s; STEP8(cx0[l].z);
                r0.w = s; STEP8(cx0[l].w);
                r1.x = s; STEP8(cx1[l].x);
                r1.y = s; STEP8(cx1[l].y);
                r1.z = s; STEP8(cx1[l].z);
                r1.w = s; STEP8(cx1[l].w);
            }
            float4* srp = (float4*)(sb + (size_t)w * WL);
            srp[0] = r0;
            srp[1] = r1;
        }
#pragma unroll
        for (int l = 0; l < GD; ++l) {
            cx0[l] = nx0[l]; cx1[l] = nx1[l]; cM[l] = nM[l];
        }
    }
}

// Output pass: fully parallel. block = (b, i), thread = j.
// Reads s_rec[b][i*NH+j] and x[b][i*NH+j] coalesced; replays the 8 substeps
// bitwise-exactly; writes outs/spikes coalesced per k-plane.
__global__ void __launch_bounds__(128)
lif_out(const float* __restrict__ x, const float* __restrict__ th,
        const float* __restrict__ s_rec, float* __restrict__ out)
{
    int j = threadIdx.x;             // 0..127
    int i = blockIdx.x & (NS - 1);
    int b = blockIdx.x >> 7;
    int t = i * NH + j;

    float s  = s_rec[(size_t)b * NT + t];
    float xv = x[(size_t)b * NT + t];

    float thr[NK];
#pragma unroll
    for (int k = 0; k < NK; ++k) thr[k] = th[k];

    float* o  = out + (((size_t)b * NS + i) * NK) * NH + j;
    float* sp = o + OUTN;
#pragma unroll
    for (int k = 0; k < NK; ++k) {
        s += xv;
        bool spike = s > thr[k];
        o[(size_t)k * NH]  = spike ? s : 0.0f;
        sp[(size_t)k * NH] = spike ? 1.0f : 0.0f;
        s = spike ? 0.0f : s;
    }
}

// Fallback if ws is too small: single-pass, scattered writes (slow, correct).
__global__ void lif_mono(const float* __restrict__ x, const float* __restrict__ th,
                         float* __restrict__ out)
{
    int b = blockIdx.x * 64 + threadIdx.x;
    if (b >= NB) return;
    float thr[NK];
#pragma unroll
    for (int k = 0; k < NK; ++k) thr[k] = th[k];
    const float* xb = x + (size_t)b * NT;
    float s = 0.0f;
    for (int i = 0; i < NS; ++i)
        for (int j = 0; j < NH; ++j) {
            float xv = xb[i * NH + j];
#pragma unroll
            for (int k = 0; k < NK; ++k) {
                s += xv;
                bool spike = s > thr[k];
                size_t idx = (((size_t)b * NS + i) * NK + k) * NH + j;
                out[idx]        = spike ? s : 0.0f;
                out[OUTN + idx] = spike ? 1.0f : 0.0f;
                s = spike ? 0.0f : s;
            }
        }
}

extern "C" void kernel_launch(void* const* d_in, const int* in_sizes, int n_in,
                              void* d_out, int out_size, void* d_ws, size_t ws_size,
                              hipStream_t stream) {
    const float* x  = (const float*)d_in[0];   // (128,128,128) fp32
    const float* th = (const float*)d_in[1];   // (8,) fp32
    float* out = (float*)d_out;

    if (ws_size >= (size_t)WS_TOTAL * sizeof(float)) {
        float* ws    = (float*)d_ws;
        float* Mbuf  = ws + WS_M;
        float* s_rec = ws + WS_SREC;

        lif_bounds8<<<dim3((NB * NW2 + 255) / 256), dim3(256), 0, stream>>>(x, th, Mbuf);
        lif_chain<<<dim3(NB), dim3(64), 0, stream>>>(x, th, Mbuf, s_rec);
        lif_out<<<dim3(NB * NS), dim3(128), 0, stream>>>(x, th, s_rec, out);
    } else {
        lif_mono<<<dim3(2), dim3(64), 0, stream>>>(x, th, out);
    }
}

// Round 7
// 537.322 us; speedup vs baseline: 1.6871x; 1.6871x over previous
//
#include <hip/hip_runtime.h>
#include <math.h>

// LIF_13984413516471 — exact serial chain, wave-cooperative staging.
// B=128, S=128, H=128, K=8. Reference: one scalar accumulator per batch,
// sequential over (i,j,k); per substep: s += x; if (s > th[k]) s = 0.
// Outputs (B,S,K,H) fp32: outs | spikes. Bitwise-exact fp32 replay.
//
// Chain: 1 batch per 64-thread block (1 wave). All lanes run the scalar
// chain redundantly (uniform); x/M arrive via coalesced wave loads ->
// LDS -> same-address broadcast ds_read (conflict-free). Quiet 8-t windows
// (certified via precomputed f64 bound M) take a pure-add fast path that is
// bitwise identical. Per-window entering states collect in lane registers
// (cndmask) and store once per 64 windows, coalesced.

#define NB 128
#define NS 128
#define NH 128
#define NK 8
#define NT (NS * NH)            // 16384 t per batch
#define WL 8                    // vote window = 8 t
#define NW2 (NT / WL)           // 2048 windows per batch
#define SWT 256                 // superwindow = 256 t = 32 windows
#define NSW (NT / SWT)          // 64 superwindows
#define NP (NSW / 2)            // 32 pairs (pair = 64 windows = 512 t)
#define OUTN ((size_t)NB * NS * NK * NH)

// ---- ws layout (floats) ----
#define WS_M     0                      // M    [NB][NW2]
#define WS_SENT  (NB * NW2)             // s_ent[NB][NW2]  (window-entry states)
#define WS_TOTAL (2 * NB * NW2)

// Per-(b,window) quiet bound, f64: M = minth - maxPrefix - margin where
// maxPrefix >= max prefix sum of the 64 substep adds from window entry.
// If entering s <= M, the real-arith chain stays >= margin below minth all
// window; fp32 drift over 64 adds at |s|<=26000 is < 0.1 = margin, so the
// fp32 chain provably never spikes -> pure adds are bitwise-exact.
__global__ void lif_bounds8(const float* __restrict__ x,
                            const float* __restrict__ th,
                            float* __restrict__ M)
{
    int idx = blockIdx.x * 256 + threadIdx.x;   // flat over NB*NW2
    if (idx >= NB * NW2) return;
    float minth = th[0];
#pragma unroll
    for (int k = 1; k < NK; ++k) minth = fminf(minth, th[k]);
    const float* xp = x + (size_t)idx * WL;     // idx = b*NW2 + w -> x[b][w*8]
    double p = 0.0, maxp = -1e300;
#pragma unroll
    for (int l = 0; l < WL; ++l) {
        double xv = (double)xp[l];
#pragma unroll
        for (int k = 0; k < NK; ++k) { p += xv; maxp = fmax(maxp, p); }
    }
    M[idx] = (float)((double)minth - maxp - 0.1 - 1e-6 * fabs(maxp));
}

#define ADD8(xv) do { s += xv; s += xv; s += xv; s += xv; \
                      s += xv; s += xv; s += xv; s += xv; } while (0)
#define STEP8(xv) do { \
    s += xv; s = (s > th0) ? 0.0f : s; \
    s += xv; s = (s > th1) ? 0.0f : s; \
    s += xv; s = (s > th2) ? 0.0f : s; \
    s += xv; s = (s > th3) ? 0.0f : s; \
    s += xv; s = (s > th4) ? 0.0f : s; \
    s += xv; s = (s > th5) ? 0.0f : s; \
    s += xv; s = (s > th6) ? 0.0f : s; \
    s += xv; s = (s > th7) ? 0.0f : s; } while (0)

__global__ void __launch_bounds__(64, 1)
lif_chain(const float* __restrict__ x, const float* __restrict__ th,
          const float* __restrict__ M, float* __restrict__ s_ent)
{
    __shared__ float xs[SWT];   // current superwindow's x (linear)
    __shared__ float Ms[64];    // current pair's 64 window bounds

    const int b = blockIdx.x;
    const int lane = threadIdx.x;
    const float4* xb4 = (const float4*)(x + (size_t)b * NT);
    const float*  Mb  = M + (size_t)b * NW2;
    float* seb = s_ent + (size_t)b * NW2;

    const float th0 = th[0], th1 = th[1], th2 = th[2], th3 = th[3];
    const float th4 = th[4], th5 = th[5], th6 = th[6], th7 = th[7];

    float s = 0.0f, keep = 0.0f;
    float4 lx = xb4[lane];      // superwindow 0 staging (1 float4/lane)
    float  lm = Mb[lane];       // pair 0 bounds (1 float/lane)

    for (int p = 0; p < NP; ++p) {
        Ms[lane] = lm;                                   // publish pair p
        lm = Mb[(size_t)((p + 1 < NP) ? p + 1 : p) * 64 + lane];  // prefetch p+1
#pragma unroll
        for (int half = 0; half < 2; ++half) {
            const int sw = 2 * p + half;
            ((float4*)xs)[lane] = lx;                    // publish sw
            lx = xb4[(size_t)((sw + 1 < NSW) ? sw + 1 : sw) * 64 + lane]; // prefetch
            // register double-buffer: window 0 of this superwindow
            float xr[8], xn[8];
#pragma unroll
            for (int m = 0; m < 8; ++m) xn[m] = xs[m];
            float Mcur = Ms[half * 32];
            for (int wi = 0; wi < 32; ++wi) {
#pragma unroll
                for (int m = 0; m < 8; ++m) xr[m] = xn[m];
                const int nwi = (wi + 1) & 31;
#pragma unroll
                for (int m = 0; m < 8; ++m) xn[m] = xs[nwi * 8 + m];
                float Mnext = Ms[half * 32 + nwi];       // wi=31: dummy (re-read at next sw)
                keep = (lane == half * 32 + wi) ? s : keep;
                int q = __builtin_amdgcn_readfirstlane((int)(s <= Mcur));
                Mcur = Mnext;
                if (q) {
                    // certified spike-free window: bitwise-identical pure adds
                    ADD8(xr[0]); ADD8(xr[1]); ADD8(xr[2]); ADD8(xr[3]);
                    ADD8(xr[4]); ADD8(xr[5]); ADD8(xr[6]); ADD8(xr[7]);
                } else {
                    STEP8(xr[0]); STEP8(xr[1]); STEP8(xr[2]); STEP8(xr[3]);
                    STEP8(xr[4]); STEP8(xr[5]); STEP8(xr[6]); STEP8(xr[7]);
                }
            }
        }
        seb[(size_t)p * 64 + lane] = keep;               // 64 windows, coalesced
    }
}

// Output pass: fully parallel, no serial section. block = (b, i), thread j.
// Lane j replays (j&7) t-steps from its window's entering state, then emits
// its own t's 8 outputs, coalesced per k-plane. Bitwise-exact replay.
__global__ void __launch_bounds__(128)
lif_out(const float* __restrict__ x, const float* __restrict__ th,
        const float* __restrict__ s_ent, float* __restrict__ out)
{
    const int j = threadIdx.x;             // 0..127
    const int i = blockIdx.x & (NS - 1);
    const int b = blockIdx.x >> 7;
    const int wl = j >> 3;                 // window within row (0..15)
    const int r  = j & 7;                  // position within window

    const float th0 = th[0], th1 = th[1], th2 = th[2], th3 = th[3];
    const float th4 = th[4], th5 = th[5], th6 = th[6], th7 = th[7];

    float s = s_ent[(size_t)b * NW2 + i * 16 + wl];
    const float* xrow = x + (size_t)b * NT + i * NH + (wl << 3);

    for (int m = 0; m < r; ++m) {          // replay to own t (<=7 steps)
        float xv = xrow[m];
        STEP8(xv);
    }
    float xv = xrow[r];

    float* o  = out + (((size_t)b * NS + i) * NK) * NH + j;
    float* sp = o + OUTN;
    float thr[NK];
#pragma unroll
    for (int k = 0; k < NK; ++k) thr[k] = th[k];
#pragma unroll
    for (int k = 0; k < NK; ++k) {
        s += xv;
        bool spike = s > thr[k];
        o[(size_t)k * NH]  = spike ? s : 0.0f;
        sp[(size_t)k * NH] = spike ? 1.0f : 0.0f;
        s = spike ? 0.0f : s;
    }
}

// Fallback if ws is too small: single-pass, scattered writes (slow, correct).
__global__ void lif_mono(const float* __restrict__ x, const float* __restrict__ th,
                         float* __restrict__ out)
{
    int b = blockIdx.x * 64 + threadIdx.x;
    if (b >= NB) return;
    float thr[NK];
#pragma unroll
    for (int k = 0; k < NK; ++k) thr[k] = th[k];
    const float* xb = x + (size_t)b * NT;
    float s = 0.0f;
    for (int i = 0; i < NS; ++i)
        for (int j = 0; j < NH; ++j) {
            float xv = xb[i * NH + j];
#pragma unroll
            for (int k = 0; k < NK; ++k) {
                s += xv;
                bool spike = s > thr[k];
                size_t idx = (((size_t)b * NS + i) * NK + k) * NH + j;
                out[idx]        = spike ? s : 0.0f;
                out[OUTN + idx] = spike ? 1.0f : 0.0f;
                s = spike ? 0.0f : s;
            }
        }
}

extern "C" void kernel_launch(void* const* d_in, const int* in_sizes, int n_in,
                              void* d_out, int out_size, void* d_ws, size_t ws_size,
                              hipStream_t stream) {
    const float* x  = (const float*)d_in[0];   // (128,128,128) fp32
    const float* th = (const float*)d_in[1];   // (8,) fp32
    float* out = (float*)d_out;

    if (ws_size >= (size_t)WS_TOTAL * sizeof(float)) {
        float* ws    = (float*)d_ws;
        float* Mbuf  = ws + WS_M;
        float* s_ent = ws + WS_SENT;

        lif_bounds8<<<dim3((NB * NW2 + 255) / 256), dim3(256), 0, stream>>>(x, th, Mbuf);
        lif_chain<<<dim3(NB), dim3(64), 0, stream>>>(x, th, Mbuf, s_ent);
        lif_out<<<dim3(NB * NS), dim3(128), 0, stream>>>(x, th, s_ent, out);
    } else {
        lif_mono<<<dim3(2), dim3(64), 0, stream>>>(x, th, out);
    }
}